// Round 1
// baseline (52505.518 us; speedup 1.0000x reference)
//
#include <hip/hip_runtime.h>
#include <hip/hip_bf16.h>
#include <math.h>

// ---------------- constants ----------------
#define Bc 128
#define Cc 112
#define Dc 1024
#define Hc 16
#define HDc 64
#define Lc 12
#define FFc 2048
#define HCc 32
#define SGHc 256
#define GENc 256
#define TOK (Bc*64)         // 8192
#define NEGV -1.0e9f

// ---------------- device math ----------------
__device__ __forceinline__ float softplusf_(float x) {
    float ax = fabsf(x);
    return fmaxf(x, 0.f) + log1pf(expf(-ax));
}
__device__ __forceinline__ float mishf_(float x) {
    return x * tanhf(softplusf_(x));
}
__device__ __forceinline__ float siluf_(float x) {
    return x / (1.f + expf(-x));
}

// ---------------- embed: h = xT @ embed_w + embed_b + pos_emb ----------------
// x: (B, C, 64) f32; h: (TOK, D)
__global__ __launch_bounds__(256) void embed_kernel(
    const float* __restrict__ x, const float* __restrict__ ew,
    const float* __restrict__ eb, const float* __restrict__ pe,
    float* __restrict__ h) {
    int tok0 = blockIdx.x * 8;
    int b = tok0 >> 6, sq0 = tok0 & 63;
    __shared__ float xs[8][Cc];
    for (int i = threadIdx.x; i < 8 * Cc; i += 256) {
        int t8 = i & 7, c = i >> 3;
        xs[t8][c] = x[((size_t)b * Cc + c) * 64 + sq0 + t8];
    }
    __syncthreads();
    #pragma unroll
    for (int j = 0; j < 4; ++j) {
        int d = threadIdx.x + j * 256;
        float acc[8];
        #pragma unroll
        for (int t = 0; t < 8; ++t) acc[t] = 0.f;
        for (int c = 0; c < Cc; ++c) {
            float w = ew[c * Dc + d];
            #pragma unroll
            for (int t = 0; t < 8; ++t) acc[t] += xs[t][c] * w;
        }
        float base = eb[d];
        #pragma unroll
        for (int t = 0; t < 8; ++t)
            h[((size_t)(tok0 + t)) * Dc + d] = acc[t] + base + pe[(size_t)(sq0 + t) * Dc + d];
    }
}

// ---------------- generic f32 GEMM: C = epi(A[M,K] @ W[K,N] + bias) ----------------
// EPI: 0 none, 1 bias, 2 bias+silu, 3 bias+mish, 4 bias+softplus
// requires K % 16 == 0
template <int EPI>
__global__ __launch_bounds__(256) void gemm_f32(
    const float* __restrict__ A, const float* __restrict__ W,
    const float* __restrict__ bias, float* __restrict__ C,
    int M, int N, int K) {
    __shared__ float As[16][64 + 1];
    __shared__ float Bs[16][64 + 2];
    int m0 = blockIdx.y * 64, n0 = blockIdx.x * 64;
    int tid = threadIdx.x;
    int ty = tid >> 4, tx = tid & 15;
    float acc[4][4] = {};
    for (int k0 = 0; k0 < K; k0 += 16) {
        #pragma unroll
        for (int i = tid; i < 64 * 16; i += 256) {
            int m = i >> 4, kk = i & 15;
            int gm = m0 + m;
            As[kk][m] = (gm < M) ? A[(size_t)gm * K + k0 + kk] : 0.f;
        }
        #pragma unroll
        for (int i = tid; i < 16 * 64; i += 256) {
            int kk = i >> 6, n = i & 63;
            int gn = n0 + n;
            Bs[kk][n] = (gn < N) ? W[(size_t)(k0 + kk) * N + gn] : 0.f;
        }
        __syncthreads();
        #pragma unroll
        for (int kk = 0; kk < 16; ++kk) {
            float a[4], bv[4];
            #pragma unroll
            for (int i = 0; i < 4; ++i) a[i] = As[kk][ty * 4 + i];
            #pragma unroll
            for (int j = 0; j < 4; ++j) bv[j] = Bs[kk][tx * 4 + j];
            #pragma unroll
            for (int i = 0; i < 4; ++i)
                #pragma unroll
                for (int j = 0; j < 4; ++j) acc[i][j] += a[i] * bv[j];
        }
        __syncthreads();
    }
    #pragma unroll
    for (int i = 0; i < 4; ++i) {
        int gm = m0 + ty * 4 + i;
        if (gm >= M) continue;
        #pragma unroll
        for (int j = 0; j < 4; ++j) {
            int gn = n0 + tx * 4 + j;
            if (gn >= N) continue;
            float v = acc[i][j];
            if (EPI >= 1) v += bias[gn];
            if (EPI == 2) v = siluf_(v);
            if (EPI == 3) v = mishf_(v);
            if (EPI == 4) v = softplusf_(v);
            C[(size_t)gm * N + gn] = v;
        }
    }
}

// ---------------- layernorm: out = ln(x (+res)) * w + b ----------------
__global__ __launch_bounds__(256) void ln_kernel(
    const float* __restrict__ x, const float* __restrict__ res,
    const float* __restrict__ w, const float* __restrict__ b,
    float* __restrict__ out, int dim) {
    int row = blockIdx.x;
    const float* xr = x + (size_t)row * dim;
    const float* rr = res ? res + (size_t)row * dim : nullptr;
    float s = 0.f, ss = 0.f;
    for (int d = threadIdx.x; d < dim; d += 256) {
        float v = xr[d] + (rr ? rr[d] : 0.f);
        s += v; ss += v * v;
    }
    #pragma unroll
    for (int o2 = 32; o2; o2 >>= 1) {
        s  += __shfl_down(s, o2);
        ss += __shfl_down(ss, o2);
    }
    __shared__ float rs[4], rss[4];
    int wid = threadIdx.x >> 6, lane = threadIdx.x & 63;
    if (lane == 0) { rs[wid] = s; rss[wid] = ss; }
    __syncthreads();
    if (threadIdx.x == 0) {
        float a = rs[0] + rs[1] + rs[2] + rs[3];
        float c = rss[0] + rss[1] + rss[2] + rss[3];
        float mu = a / dim;
        float var = c / dim - mu * mu;
        rs[0] = mu;
        rss[0] = rsqrtf(fmaxf(var, 0.f) + 1e-5f);
    }
    __syncthreads();
    float mu = rs[0], inv = rss[0];
    float* orow = out + (size_t)row * dim;
    for (int d = threadIdx.x; d < dim; d += 256) {
        float v = xr[d] + (rr ? rr[d] : 0.f);
        orow[d] = (v - mu) * inv * w[d] + b[d];
    }
}

// ---------------- per-head RMS norm over HD=64, in place ----------------
// q layout: (TOK, D) with head h at cols h*64..h*64+63. One wave per (tok,h).
__global__ __launch_bounds__(256) void rms_qk(float* __restrict__ q,
                                              const float* __restrict__ w) {
    int g = blockIdx.x * 4 + (threadIdx.x >> 6);   // g = tok*16 + h
    int lane = threadIdx.x & 63;
    size_t idx = (size_t)(g >> 4) * Dc + (size_t)(g & 15) * 64 + lane;
    float v = q[idx];
    float ss = v * v;
    #pragma unroll
    for (int o2 = 32; o2; o2 >>= 1) ss += __shfl_down(ss, o2);
    ss = __shfl(ss, 0);
    float sc = rsqrtf(ss * (1.f / 64.f) + 1e-6f);
    q[idx] = v * sc * w[lane];
}

// ---------------- attention: one block per (b,h) ----------------
// q,k,v: (TOK, D); bias: (B*H, 64*64); o: (TOK, D)
__global__ __launch_bounds__(256) void attn_kernel(
    const float* __restrict__ q, const float* __restrict__ k,
    const float* __restrict__ v, const float* __restrict__ bias,
    float* __restrict__ o) {
    int bh = blockIdx.x;
    int b = bh >> 4, h = bh & 15;
    __shared__ float ps[64][65];   // holds Q first, then probs
    __shared__ float ks[64][65];
    __shared__ float vs[64][65];
    for (int i = threadIdx.x; i < 64 * 64; i += 256) {
        int r = i >> 6, c = i & 63;
        size_t base = ((size_t)(b * 64 + r)) * Dc + h * 64 + c;
        ps[r][c] = q[base];
        ks[r][c] = k[base];
        vs[r][c] = v[base];
    }
    __syncthreads();
    int qi = threadIdx.x >> 2;
    int kb4 = (threadIdx.x & 3) * 16;
    float lg[16];
    #pragma unroll
    for (int kk = 0; kk < 16; ++kk) lg[kk] = 0.f;
    for (int hd = 0; hd < 64; ++hd) {
        float qv = ps[qi][hd];
        #pragma unroll
        for (int kk = 0; kk < 16; ++kk) lg[kk] += qv * ks[kb4 + kk][hd];
    }
    const float* brow = bias + ((size_t)bh * 64 + qi) * 64 + kb4;
    #pragma unroll
    for (int kk = 0; kk < 16; ++kk) lg[kk] = lg[kk] * 0.125f + brow[kk];
    __syncthreads();           // all reads of ps(Q) done
    #pragma unroll
    for (int kk = 0; kk < 16; ++kk) ps[qi][kb4 + kk] = lg[kk];
    __syncthreads();
    if (threadIdx.x < 64) {
        int r = threadIdx.x;
        float m = -INFINITY;
        for (int kk = 0; kk < 64; ++kk) m = fmaxf(m, ps[r][kk]);
        float sum = 0.f;
        for (int kk = 0; kk < 64; ++kk) { float e = expf(ps[r][kk] - m); ps[r][kk] = e; sum += e; }
        float inv = 1.f / sum;
        for (int kk = 0; kk < 64; ++kk) ps[r][kk] *= inv;
    }
    __syncthreads();
    int hb = (threadIdx.x & 3) * 16;
    float acc[16];
    #pragma unroll
    for (int j = 0; j < 16; ++j) acc[j] = 0.f;
    for (int kk = 0; kk < 64; ++kk) {
        float pv = ps[qi][kk];
        #pragma unroll
        for (int j = 0; j < 16; ++j) acc[j] += pv * vs[kk][hb + j];
    }
    size_t ob = ((size_t)(b * 64 + qi)) * Dc + h * 64 + hb;
    #pragma unroll
    for (int j = 0; j < 16; ++j) o[ob + j] = acc[j];
}

// ---------------- policy from-to logits: lft[b] = q[b] @ k[b]^T * D^-0.5 ----------------
__global__ __launch_bounds__(256) void lft_kernel(
    const float* __restrict__ q, const float* __restrict__ k, float* __restrict__ lft) {
    int b = blockIdx.x;
    int ty = threadIdx.x >> 4, tx = threadIdx.x & 15;
    __shared__ float qs[64][65], ks[64][65];
    float acc[4][4] = {};
    for (int d0 = 0; d0 < Dc; d0 += 64) {
        for (int i = threadIdx.x; i < 4096; i += 256) {
            int r = i >> 6, c = i & 63;
            size_t base = ((size_t)(b * 64 + r)) * Dc + d0 + c;
            qs[r][c] = q[base];
            ks[r][c] = k[base];
        }
        __syncthreads();
        #pragma unroll
        for (int dd = 0; dd < 64; ++dd) {
            float av[4], bv[4];
            #pragma unroll
            for (int i = 0; i < 4; ++i) av[i] = qs[ty * 4 + i][dd];
            #pragma unroll
            for (int j = 0; j < 4; ++j) bv[j] = ks[tx * 4 + j][dd];
            #pragma unroll
            for (int i = 0; i < 4; ++i)
                #pragma unroll
                for (int j = 0; j < 4; ++j) acc[i][j] += av[i] * bv[j];
        }
        __syncthreads();
    }
    #pragma unroll
    for (int i = 0; i < 4; ++i)
        #pragma unroll
        for (int j = 0; j < 4; ++j)
            lft[((size_t)b * 64 + ty * 4 + i) * 64 + tx * 4 + j] = acc[i][j] * 0.03125f;
}

// ---------------- policy gather into 64x73 LC0 planes ----------------
__device__ const int g_drs[8] = {1, 1, 0, -1, -1, -1, 0, 1};
__device__ const int g_dcs[8] = {0, 1, 1, 1, 0, -1, -1, -1};
__device__ const int g_krs[8] = {2, 1, -1, -2, -2, -1, 1, 2};
__device__ const int g_kcs[8] = {1, 2, 2, 1, -1, -2, -2, -1};

__global__ __launch_bounds__(256) void policy_kernel(
    const float* __restrict__ lft, const float* __restrict__ up, float* __restrict__ out) {
    int idx = blockIdx.x * 256 + threadIdx.x;     // < B*64*73
    int b = idx / (64 * 73);
    int r = idx - b * (64 * 73);
    int f = r / 73, p = r - f * 73;
    int fr = f >> 3, fc = f & 7;
    float val;
    if (p < 64) {
        int nr, nc;
        if (p < 56) {
            int d = p / 7, dist = p - d * 7 + 1;
            nr = fr + g_drs[d] * dist; nc = fc + g_dcs[d] * dist;
        } else {
            int i = p - 56;
            nr = fr + g_krs[i]; nc = fc + g_kcs[i];
        }
        bool ok = (nr >= 0 && nr < 8 && nc >= 0 && nc < 8);
        int to = ok ? (nr * 8 + nc) : 0;
        val = ok ? lft[((size_t)b * 64 + f) * 64 + to] : NEGV;
    } else {
        val = (fr == 6) ? up[((size_t)b * 64 + f) * 9 + (p - 64)] : NEGV;
    }
    out[idx] = val;
}

// ---------------- pooled mean over 64 tokens ----------------
__global__ __launch_bounds__(256) void pool_kernel(const float* __restrict__ h,
                                                   float* __restrict__ pooled) {
    int b = blockIdx.x;
    int d = threadIdx.x + blockIdx.y * 256;
    float s = 0.f;
    for (int sq = 0; sq < 64; ++sq) s += h[((size_t)b * 64 + sq) * Dc + d];
    pooled[(size_t)b * Dc + d] = s * (1.f / 64.f);
}

// ---------------- host launcher ----------------
static inline dim3 gemm_grid(int M, int N) { return dim3((N + 63) / 64, (M + 63) / 64); }

extern "C" void kernel_launch(void* const* d_in, const int* in_sizes, int n_in,
                              void* d_out, int out_size, void* d_ws, size_t ws_size,
                              hipStream_t stream) {
    int ii = 0;
    const float* x        = (const float*)d_in[ii++];
    const float* embed_w  = (const float*)d_in[ii++];
    const float* embed_b  = (const float*)d_in[ii++];
    const float* pos_emb  = (const float*)d_in[ii++];
    const float* Wq = (const float*)d_in[ii++]; const float* bq = (const float*)d_in[ii++];
    const float* Wk = (const float*)d_in[ii++]; const float* bk = (const float*)d_in[ii++];
    const float* Wv = (const float*)d_in[ii++]; const float* bv = (const float*)d_in[ii++];
    const float* Wo = (const float*)d_in[ii++]; const float* bo = (const float*)d_in[ii++];
    const float* qn_w = (const float*)d_in[ii++]; const float* kn_w = (const float*)d_in[ii++];
    const float* ln1_w = (const float*)d_in[ii++]; const float* ln1_b = (const float*)d_in[ii++];
    const float* ln2_w = (const float*)d_in[ii++]; const float* ln2_b = (const float*)d_in[ii++];
    const float* ff_w1 = (const float*)d_in[ii++]; const float* ff_b1 = (const float*)d_in[ii++];
    const float* ff_w2 = (const float*)d_in[ii++]; const float* ff_b2 = (const float*)d_in[ii++];
    const float* sg_c_w = (const float*)d_in[ii++];
    const float* sg_d1_w = (const float*)d_in[ii++]; const float* sg_d1_b = (const float*)d_in[ii++];
    const float* sg_ln1_w = (const float*)d_in[ii++]; const float* sg_ln1_b = (const float*)d_in[ii++];
    const float* sg_d2_w = (const float*)d_in[ii++]; const float* sg_d2_b = (const float*)d_in[ii++];
    const float* sg_ln2_w = (const float*)d_in[ii++]; const float* sg_ln2_b = (const float*)d_in[ii++];
    const float* sg_gen_w = (const float*)d_in[ii++];
    const float* pq_w = (const float*)d_in[ii++]; const float* pq_b = (const float*)d_in[ii++];
    const float* pk_w = (const float*)d_in[ii++]; const float* pk_b = (const float*)d_in[ii++];
    const float* up_w = (const float*)d_in[ii++]; const float* up_b = (const float*)d_in[ii++];
    const float* vt_w = (const float*)d_in[ii++]; const float* vt_b = (const float*)d_in[ii++];
    const float* v1_w = (const float*)d_in[ii++]; const float* v1_b = (const float*)d_in[ii++];
    const float* v2_w = (const float*)d_in[ii++]; const float* v2_b = (const float*)d_in[ii++];
    const float* sc1_w = (const float*)d_in[ii++]; const float* sc1_b = (const float*)d_in[ii++];
    const float* sc2_w = (const float*)d_in[ii++]; const float* sc2_b = (const float*)d_in[ii++];
    const float* vo1_w = (const float*)d_in[ii++]; const float* vo1_b = (const float*)d_in[ii++];
    const float* vo2_w = (const float*)d_in[ii++]; const float* vo2_b = (const float*)d_in[ii++];
    float* out = (float*)d_out;

    // workspace carve-up (floats)
    float* ws = (float*)d_ws;
    size_t off = 0;
    float* h   = ws + off; off += (size_t)TOK * Dc;
    float* qb  = ws + off; off += (size_t)TOK * Dc;
    float* kb  = ws + off; off += (size_t)TOK * Dc;
    float* vb  = ws + off; off += (size_t)TOK * Dc;
    float* ob  = ws + off; off += (size_t)TOK * Dc;
    float* tb  = ws + off; off += (size_t)TOK * FFc;   // ff intermediate / smolgen bias
    float* hcb = ws + off; off += (size_t)TOK * HCc;
    float* s1  = ws + off; off += (size_t)Bc * SGHc;
    float* s2  = ws + off; off += (size_t)Bc * (Hc * GENc);
    float* lft = ws + off; off += (size_t)Bc * 64 * 64;
    float* upb = ws + off; off += (size_t)TOK * 9;
    float* pooled = ws + off; off += (size_t)Bc * Dc;
    float* val1 = ws + off; off += (size_t)Bc * 128;
    float* sc32 = ws + off; off += (size_t)Bc * 32;
    float* vo64 = ws + off; off += (size_t)Bc * 64;
    float* vtb  = ws + off; off += (size_t)TOK * 128;
    (void)off; (void)ws_size; (void)in_sizes; (void)n_in; (void)out_size;

    // ---- embed ----
    embed_kernel<<<TOK / 8, 256, 0, stream>>>(x, embed_w, embed_b, pos_emb, h);

    // ---- transformer layers ----
    for (int i = 0; i < Lc; ++i) {
        const float* wq = Wq + (size_t)i * Dc * Dc;
        const float* wk = Wk + (size_t)i * Dc * Dc;
        const float* wv = Wv + (size_t)i * Dc * Dc;
        const float* wo = Wo + (size_t)i * Dc * Dc;

        // smolgen
        gemm_f32<0><<<gemm_grid(TOK, HCc), 256, 0, stream>>>(
            h, sg_c_w + (size_t)i * Dc * HCc, nullptr, hcb, TOK, HCc, Dc);
        gemm_f32<2><<<gemm_grid(Bc, SGHc), 256, 0, stream>>>(
            hcb, sg_d1_w + (size_t)i * 2048 * SGHc, sg_d1_b + (size_t)i * SGHc, s1, Bc, SGHc, 2048);
        ln_kernel<<<Bc, 256, 0, stream>>>(s1, nullptr, sg_ln1_w + (size_t)i * SGHc,
                                          sg_ln1_b + (size_t)i * SGHc, s1, SGHc);
        gemm_f32<2><<<gemm_grid(Bc, Hc * GENc), 256, 0, stream>>>(
            s1, sg_d2_w + (size_t)i * SGHc * (Hc * GENc), sg_d2_b + (size_t)i * (Hc * GENc),
            s2, Bc, Hc * GENc, SGHc);
        ln_kernel<<<Bc, 256, 0, stream>>>(s2, nullptr, sg_ln2_w + (size_t)i * (Hc * GENc),
                                          sg_ln2_b + (size_t)i * (Hc * GENc), s2, Hc * GENc);
        // bias (B*H, 4096) into tb
        gemm_f32<0><<<gemm_grid(Bc * Hc, 4096), 256, 0, stream>>>(
            s2, sg_gen_w + (size_t)i * GENc * 4096, nullptr, tb, Bc * Hc, 4096, GENc);

        // qkv
        gemm_f32<1><<<gemm_grid(TOK, Dc), 256, 0, stream>>>(
            h, wq, bq + (size_t)i * Dc, qb, TOK, Dc, Dc);
        gemm_f32<1><<<gemm_grid(TOK, Dc), 256, 0, stream>>>(
            h, wk, bk + (size_t)i * Dc, kb, TOK, Dc, Dc);
        gemm_f32<1><<<gemm_grid(TOK, Dc), 256, 0, stream>>>(
            h, wv, bv + (size_t)i * Dc, vb, TOK, Dc, Dc);
        rms_qk<<<TOK * Hc / 4, 256, 0, stream>>>(qb, qn_w + (size_t)i * HDc);
        rms_qk<<<TOK * Hc / 4, 256, 0, stream>>>(kb, kn_w + (size_t)i * HDc);

        attn_kernel<<<Bc * Hc, 256, 0, stream>>>(qb, kb, vb, tb, ob);

        // out proj + residual LN  (qb reused as scratch)
        gemm_f32<1><<<gemm_grid(TOK, Dc), 256, 0, stream>>>(
            ob, wo, bo + (size_t)i * Dc, qb, TOK, Dc, Dc);
        ln_kernel<<<TOK, 256, 0, stream>>>(qb, h, ln1_w + (size_t)i * Dc,
                                           ln1_b + (size_t)i * Dc, h, Dc);

        // FF
        gemm_f32<3><<<gemm_grid(TOK, FFc), 256, 0, stream>>>(
            h, ff_w1 + (size_t)i * Dc * FFc, ff_b1 + (size_t)i * FFc, tb, TOK, FFc, Dc);
        gemm_f32<1><<<gemm_grid(TOK, Dc), 256, 0, stream>>>(
            tb, ff_w2 + (size_t)i * FFc * Dc, ff_b2 + (size_t)i * Dc, qb, TOK, Dc, FFc);
        ln_kernel<<<TOK, 256, 0, stream>>>(qb, h, ln2_w + (size_t)i * Dc,
                                           ln2_b + (size_t)i * Dc, h, Dc);
    }

    // ---- policy head ----
    gemm_f32<1><<<gemm_grid(TOK, Dc), 256, 0, stream>>>(h, pq_w, pq_b, qb, TOK, Dc, Dc);
    gemm_f32<1><<<gemm_grid(TOK, Dc), 256, 0, stream>>>(h, pk_w, pk_b, kb, TOK, Dc, Dc);
    lft_kernel<<<Bc, 256, 0, stream>>>(qb, kb, lft);
    gemm_f32<1><<<gemm_grid(TOK, 9), 256, 0, stream>>>(h, up_w, up_b, upb, TOK, 9, Dc);
    policy_kernel<<<(Bc * 64 * 73) / 256, 256, 0, stream>>>(lft, upb, out);

    // ---- value head ----
    gemm_f32<3><<<gemm_grid(TOK, 128), 256, 0, stream>>>(h, vt_w, vt_b, vtb, TOK, 128, Dc);
    gemm_f32<3><<<gemm_grid(Bc, 128), 256, 0, stream>>>(vtb, v1_w, v1_b, val1, Bc, 128, 64 * 128);
    gemm_f32<1><<<gemm_grid(Bc, 3), 256, 0, stream>>>(val1, v2_w, v2_b,
                                                      out + (size_t)Bc * 4672, Bc, 3, 128);

    // ---- scalar / vol heads ----
    pool_kernel<<<dim3(Bc, Dc / 256), 256, 0, stream>>>(h, pooled);
    gemm_f32<3><<<gemm_grid(Bc, 32), 256, 0, stream>>>(pooled, sc1_w, sc1_b, sc32, Bc, 32, Dc);
    gemm_f32<1><<<gemm_grid(Bc, 1), 256, 0, stream>>>(sc32, sc2_w, sc2_b,
                                                      out + (size_t)Bc * 4672 + Bc * 3, Bc, 1, 32);
    gemm_f32<3><<<gemm_grid(Bc, 64), 256, 0, stream>>>(pooled, vo1_w, vo1_b, vo64, Bc, 64, Dc);
    gemm_f32<4><<<gemm_grid(Bc, 3), 256, 0, stream>>>(vo64, vo2_w, vo2_b,
                                                      out + (size_t)Bc * 4672 + Bc * 4, Bc, 3, 64);
}